// Round 14
// baseline (628.574 us; speedup 1.0000x reference)
//
#include <hip/hip_runtime.h>
#include <hip/hip_bf16.h>
#include <stdint.h>

typedef float floatx2 __attribute__((ext_vector_type(2)));
typedef unsigned uint32x4 __attribute__((ext_vector_type(4)));

__device__ __forceinline__ float rdlane(float v, int l) {
    return __uint_as_float(__builtin_amdgcn_readlane(__float_as_uint(v), l));
}
// pack floats -> fp8 e4m3 (HW cvt, RNE)
__device__ __forceinline__ unsigned pk_fp8x4(float a, float b, float c, float d) {
    int u = __builtin_amdgcn_cvt_pk_fp8_f32(a, b, 0, false);
    u = __builtin_amdgcn_cvt_pk_fp8_f32(c, d, u, true);
    return (unsigned)u;
}
__device__ __forceinline__ unsigned pk_fp8x2(float a, float b) {
    return (unsigned)__builtin_amdgcn_cvt_pk_fp8_f32(a, b, 0, false);
}

// ---------------- zero 8-way partitioned counters + pooled sums -------------
__global__ void k_zero(int* __restrict__ cntO8, int* __restrict__ cntI8,
                       double* __restrict__ sums, int n8) {
    int i = blockIdx.x * blockDim.x + threadIdx.x;
    if (i < 128) sums[i] = 0.0;
    if (i < n8) { cntO8[i] = 0; cntI8[i] = 0; }
}

// ------- FUSED front: edge MLP + XCD-partitioned rank atomics ---------------
// part = blockIdx&7: each counter copy is touched by one XCD class only ->
// atomics should execute in that XCD's L2 (no memory-side RMW).
__global__ __launch_bounds__(256) void k_front(
    const int* __restrict__ ei, const float* __restrict__ ea,
    const float* __restrict__ We1, const float* __restrict__ be1,
    const float* __restrict__ We2, const float* __restrict__ be2,
    uint2* __restrict__ efp, int* __restrict__ cntO8, int* __restrict__ cntI8,
    int* __restrict__ rankS, int* __restrict__ rankD, int E, int N) {
    __shared__ float sWe1[128], sbe1[64], sWe2[64 * 6], sbe2[6];
    int t = threadIdx.x;
    if (t < 128) sWe1[t] = We1[t];
    if (t < 64) {
        sbe1[t] = be1[t];
#pragma unroll
        for (int c = 0; c < 6; ++c) sWe2[t * 6 + c] = We2[t * 64 + c];
    }
    if (t < 6) sbe2[t] = be2[t];
    __syncthreads();

    int e = blockIdx.x * blockDim.x + t;
    if (e >= E) return;
    int part = blockIdx.x & 7;

    int s = ei[e], d = ei[E + e];
    int rs = atomicAdd(&cntO8[(size_t)part * N + s], 1);  // issue early
    int rd = atomicAdd(&cntI8[(size_t)part * N + d], 1);  // MLP overlaps RMW

    float2 aa = ((const float2*)ea)[e];
    float acc[6];
#pragma unroll
    for (int c = 0; c < 6; ++c) acc[c] = sbe2[c];
#pragma unroll
    for (int j = 0; j < 64; ++j) {
        float h = fmaf(aa.x, sWe1[j], fmaf(aa.y, sWe1[64 + j], sbe1[j]));
        h = fmaxf(h, 0.f);
#pragma unroll
        for (int c = 0; c < 6; ++c) acc[c] = fmaf(h, sWe2[j * 6 + c], acc[c]);
    }
    efp[e] = make_uint2(pk_fp8x4(acc[0], acc[1], acc[2], acc[3]),
                        pk_fp8x2(acc[4], acc[5]));
    rankS[e] = rs;
    rankD[e] = rd;
}

// ------- column scan: cnt[8][i] -> exclusive bases in place + totals --------
__global__ __launch_bounds__(256) void k_colscan(int* __restrict__ cntO8,
                                                 int* __restrict__ cntI8,
                                                 int* __restrict__ totO,
                                                 int* __restrict__ totI, int n) {
    int i = blockIdx.x * blockDim.x + threadIdx.x;
    if (i >= n) return;
    int run = 0;
#pragma unroll
    for (int p = 0; p < 8; ++p) {
        int v = cntO8[(size_t)p * n + i];
        cntO8[(size_t)p * n + i] = run;
        run += v;
    }
    totO[i] = run;
    run = 0;
#pragma unroll
    for (int p = 0; p < 8; ++p) {
        int v = cntI8[(size_t)p * n + i];
        cntI8[(size_t)p * n + i] = run;
        run += v;
    }
    totI[i] = run;
}

// ---------------- fused int2 scan (3 passes) --------------------------------
__global__ __launch_bounds__(256) void k_scan1(const int* __restrict__ cntO,
                                               const int* __restrict__ cntI,
                                               int2* __restrict__ bsum, int n) {
    __shared__ int2 l[256];
    int i = blockIdx.x * 256 + threadIdx.x;
    l[threadIdx.x] = (i < n) ? make_int2(cntO[i], cntI[i]) : make_int2(0, 0);
    __syncthreads();
    for (int s = 128; s > 0; s >>= 1) {
        if (threadIdx.x < s) {
            l[threadIdx.x].x += l[threadIdx.x + s].x;
            l[threadIdx.x].y += l[threadIdx.x + s].y;
        }
        __syncthreads();
    }
    if (threadIdx.x == 0) bsum[blockIdx.x] = l[0];
}
__global__ __launch_bounds__(512) void k_scan2(int2* __restrict__ bsum, int nb,
                                               int* __restrict__ offON,
                                               int* __restrict__ offIN) {
    __shared__ int2 l[512];
    int t = threadIdx.x;
    int2 v = (t < nb) ? bsum[t] : make_int2(0, 0);
    l[t] = v;
    __syncthreads();
    for (int s = 1; s < 512; s <<= 1) {
        int2 tmp = (t >= s) ? l[t - s] : make_int2(0, 0);
        __syncthreads();
        l[t].x += tmp.x; l[t].y += tmp.y;
        __syncthreads();
    }
    if (t < nb) bsum[t] = make_int2(l[t].x - v.x, l[t].y - v.y);
    if (t == 511) { *offON = l[511].x; *offIN = l[511].y; }
}
__global__ __launch_bounds__(256) void k_scan3off(const int* __restrict__ cntO,
                                                  const int* __restrict__ cntI,
                                                  const int2* __restrict__ bsum,
                                                  int* __restrict__ offO,
                                                  int* __restrict__ offI, int n) {
    __shared__ int2 l[256];
    int i = blockIdx.x * 256 + threadIdx.x;
    int2 v = (i < n) ? make_int2(cntO[i], cntI[i]) : make_int2(0, 0);
    l[threadIdx.x] = v;
    __syncthreads();
    for (int s = 1; s < 256; s <<= 1) {
        int2 tmp = (threadIdx.x >= (unsigned)s) ? l[threadIdx.x - s] : make_int2(0, 0);
        __syncthreads();
        l[threadIdx.x].x += tmp.x; l[threadIdx.x].y += tmp.y;
        __syncthreads();
    }
    if (i < n) {
        int2 bs = bsum[blockIdx.x];
        offO[i] = l[threadIdx.x].x - v.x + bs.x;
        offI[i] = l[threadIdx.x].y - v.y + bs.y;
    }
}

// ------- CSR placement: slot = off[node] + base[part][node] + rank ----------
__global__ __launch_bounds__(256) void k_place(const int* __restrict__ ei,
                                               const int* __restrict__ rankS,
                                               const int* __restrict__ rankD,
                                               const int* __restrict__ offO,
                                               const int* __restrict__ offI,
                                               const int* __restrict__ baseO8,
                                               const int* __restrict__ baseI8,
                                               const uint2* __restrict__ efp,
                                               uint2* __restrict__ out_rec,
                                               uint4* __restrict__ in_rec,
                                               int E, int N) {
    int e = blockIdx.x * blockDim.x + threadIdx.x;
    if (e >= E) return;
    int part = blockIdx.x & 7;   // must match k_front's grid mapping
    int s = ei[e], d = ei[E + e];
    uint2 f = efp[e];
    out_rec[offO[s] + baseO8[(size_t)part * N + s] + rankS[e]] = f;
    in_rec[offI[d] + baseI8[(size_t)part * N + d] + rankD[e]] =
        make_uint4((unsigned)s, f.x, f.y, 0u);
}

// ------- per node: nef sums + dinv + in_src emit + FUSED layer-1 matmul -----
__global__ __launch_bounds__(256) void k_nefmm1(
    const int* __restrict__ offO, const uint2* __restrict__ out_rec,
    const int* __restrict__ offI, const uint4* __restrict__ in_rec,
    const float* __restrict__ x, const float* __restrict__ W1,
    float* __restrict__ dinv, int* __restrict__ in_src,
    unsigned* __restrict__ sOut, int n) {
    __shared__ float sW1[384];
    int t = threadIdx.x;
    for (int idx = t; idx < 384; idx += 256) sW1[idx] = W1[idx];
    __syncthreads();

    int i = blockIdx.x * blockDim.x + t;
    if (i >= n) return;
    int bo = offO[i], eo = offO[i + 1];
    int bi = offI[i], eiN = offI[i + 1];
    float a0 = 0.f, a1 = 0.f, a2 = 0.f, a3 = 0.f, a4 = 0.f, a5 = 0.f;
    for (int j = bo; j < eo; ++j) {
        uint2 q = out_rec[j];
        floatx2 p01 = __builtin_amdgcn_cvt_pk_f32_fp8(q.x, false);
        floatx2 p23 = __builtin_amdgcn_cvt_pk_f32_fp8(q.x, true);
        floatx2 p45 = __builtin_amdgcn_cvt_pk_f32_fp8(q.y, false);
        a0 += p01.x; a1 += p01.y; a2 += p23.x;
        a3 += p23.y; a4 += p45.x; a5 += p45.y;
    }
    for (int j = bi; j < eiN; ++j) {
        uint4 r = in_rec[j];
        __builtin_nontemporal_store((int)r.x, in_src + j);   // compact stream
        floatx2 p01 = __builtin_amdgcn_cvt_pk_f32_fp8(r.y, false);
        floatx2 p23 = __builtin_amdgcn_cvt_pk_f32_fp8(r.y, true);
        floatx2 p45 = __builtin_amdgcn_cvt_pk_f32_fp8(r.z, false);
        a0 += p01.x; a1 += p01.y; a2 += p23.x;
        a3 += p23.y; a4 += p45.x; a5 += p45.y;
    }
    int indeg = eiN - bi;
    float degf = (float)((eo - bo) + indeg);
    float inv = 0.5f / fmaxf(degf, 1.f);
    const float2* xr = (const float2*)(x + (size_t)i * 6);
    float2 x01 = xr[0], x23 = xr[1], x45 = xr[2];
    float xp0 = x01.x + a0 * inv, xp1 = x01.y + a1 * inv;
    float xp2 = x23.x + a2 * inv, xp3 = x23.y + a3 * inv;
    float xp4 = x45.x + a4 * inv, xp5 = x45.y + a5 * inv;
    float dv = 1.f / sqrtf(1.f + (float)indeg);
    dinv[i] = dv;

    // layer 1: s1 = fp8(dv * (xp @ W1)) -> 16 packed uints (64B row)
    unsigned u[16];
#pragma unroll
    for (int c4 = 0; c4 < 16; ++c4) {
        float tv[4];
#pragma unroll
        for (int k = 0; k < 4; ++k) {
            int c = c4 * 4 + k;
            float v = xp0 * sW1[c] + xp1 * sW1[64 + c] + xp2 * sW1[128 + c]
                    + xp3 * sW1[192 + c] + xp4 * sW1[256 + c] + xp5 * sW1[320 + c];
            tv[k] = v * dv;
        }
        u[c4] = pk_fp8x4(tv[0], tv[1], tv[2], tv[3]);
    }
#pragma unroll
    for (int q4 = 0; q4 < 4; ++q4) {
        uint32x4 v = {u[q4 * 4 + 0], u[q4 * 4 + 1], u[q4 * 4 + 2], u[q4 * 4 + 3]};
        __builtin_nontemporal_store(v, (uint32x4*)(sOut + (size_t)i * 16) + q4);
    }
}

// ------- FUSED gather+mm, fp8 rows (64B): 16 lanes x uint per row -----------
__global__ __launch_bounds__(256) void k_gathermm(
    const int* __restrict__ offI, const int* __restrict__ in_src,
    const float* __restrict__ dinv, const unsigned* __restrict__ sIn,
    const float* __restrict__ bias, const float* __restrict__ W,
    unsigned* __restrict__ sOut, int n) {
    int lane = threadIdx.x & 63;
    int sub = lane & 15, grp = lane >> 4;
    int wid = (blockIdx.x * blockDim.x + threadIdx.x) >> 6;
    int nw = (gridDim.x * blockDim.x) >> 6;
    float w[64];
#pragma unroll
    for (int c = 0; c < 64; ++c) w[c] = W[c * 64 + lane];
    float4 bb = ((const float4*)bias)[sub];

    for (int i = wid; i < n; i += nw) {
        unsigned su = sIn[(size_t)i * 16 + sub];
        float a0, a1, a2, a3;
        if (grp == 0) {
            floatx2 lo = __builtin_amdgcn_cvt_pk_f32_fp8(su, false);
            floatx2 hi = __builtin_amdgcn_cvt_pk_f32_fp8(su, true);
            a0 = lo.x; a1 = lo.y; a2 = hi.x; a3 = hi.y;
        } else { a0 = a1 = a2 = a3 = 0.f; }
        int b0 = offI[i], e0 = offI[i + 1];
#pragma unroll 4
        for (int j = b0 + grp; j < e0; j += 4) {
            unsigned src = (unsigned)__builtin_nontemporal_load(in_src + j);
            unsigned u = sIn[(size_t)src * 16 + sub];
            floatx2 lo = __builtin_amdgcn_cvt_pk_f32_fp8(u, false);
            floatx2 hi = __builtin_amdgcn_cvt_pk_f32_fp8(u, true);
            a0 += lo.x; a1 += lo.y; a2 += hi.x; a3 += hi.y;
        }
        a0 += __shfl_xor(a0, 16); a1 += __shfl_xor(a1, 16);
        a2 += __shfl_xor(a2, 16); a3 += __shfl_xor(a3, 16);
        a0 += __shfl_xor(a0, 32); a1 += __shfl_xor(a1, 32);
        a2 += __shfl_xor(a2, 32); a3 += __shfl_xor(a3, 32);

        float dv = dinv[i];
        float h0 = fmaxf(fmaf(a0, dv, bb.x), 0.f);
        float h1 = fmaxf(fmaf(a1, dv, bb.y), 0.f);
        float h2 = fmaxf(fmaf(a2, dv, bb.z), 0.f);
        float h3 = fmaxf(fmaf(a3, dv, bb.w), 0.f);
        float o = 0.f;
#pragma unroll
        for (int g = 0; g < 16; ++g) {
            o = fmaf(rdlane(h0, g), w[g * 4 + 0], o);
            o = fmaf(rdlane(h1, g), w[g * 4 + 1], o);
            o = fmaf(rdlane(h2, g), w[g * 4 + 2], o);
            o = fmaf(rdlane(h3, g), w[g * 4 + 3], o);
        }
        o *= dv;
        float o0 = __shfl(o, sub * 4 + 0);
        float o1 = __shfl(o, sub * 4 + 1);
        float o2 = __shfl(o, sub * 4 + 2);
        float o3 = __shfl(o, sub * 4 + 3);
        if (lane < 16)
            __builtin_nontemporal_store(pk_fp8x4(o0, o1, o2, o3),
                                        sOut + (size_t)i * 16 + lane);
    }
}

// ------- FUSED final gather + b3 + pooled sum/sumsq, fp8 rows ---------------
__global__ __launch_bounds__(256) void k_gatherreduce(
    const int* __restrict__ offI, const int* __restrict__ in_src,
    const float* __restrict__ dinv, const unsigned* __restrict__ sIn,
    const float* __restrict__ b3, double* __restrict__ sums, int n) {
    int lane = threadIdx.x & 63;
    int sub = lane & 15, grp = lane >> 4;
    int wv = threadIdx.x >> 6;
    int wid = (blockIdx.x * blockDim.x + threadIdx.x) >> 6;
    int nw = (gridDim.x * blockDim.x) >> 6;
    float4 bb = ((const float4*)b3)[sub];
    double s0 = 0.0, s1 = 0.0, s2_ = 0.0, s3 = 0.0;
    double q0 = 0.0, q1 = 0.0, q2 = 0.0, q3 = 0.0;

    for (int i = wid; i < n; i += nw) {
        unsigned su = sIn[(size_t)i * 16 + sub];
        float a0, a1, a2, a3;
        if (grp == 0) {
            floatx2 lo = __builtin_amdgcn_cvt_pk_f32_fp8(su, false);
            floatx2 hi = __builtin_amdgcn_cvt_pk_f32_fp8(su, true);
            a0 = lo.x; a1 = lo.y; a2 = hi.x; a3 = hi.y;
        } else { a0 = a1 = a2 = a3 = 0.f; }
        int b0 = offI[i], e0 = offI[i + 1];
#pragma unroll 4
        for (int j = b0 + grp; j < e0; j += 4) {
            unsigned src = (unsigned)__builtin_nontemporal_load(in_src + j);
            unsigned u = sIn[(size_t)src * 16 + sub];
            floatx2 lo = __builtin_amdgcn_cvt_pk_f32_fp8(u, false);
            floatx2 hi = __builtin_amdgcn_cvt_pk_f32_fp8(u, true);
            a0 += lo.x; a1 += lo.y; a2 += hi.x; a3 += hi.y;
        }
        a0 += __shfl_xor(a0, 16); a1 += __shfl_xor(a1, 16);
        a2 += __shfl_xor(a2, 16); a3 += __shfl_xor(a3, 16);
        a0 += __shfl_xor(a0, 32); a1 += __shfl_xor(a1, 32);
        a2 += __shfl_xor(a2, 32); a3 += __shfl_xor(a3, 32);

        float dv = dinv[i];
        float v0 = fmaf(a0, dv, bb.x);
        float v1 = fmaf(a1, dv, bb.y);
        float v2 = fmaf(a2, dv, bb.z);
        float v3 = fmaf(a3, dv, bb.w);
        s0 += v0; s1 += v1; s2_ += v2; s3 += v3;
        q0 += (double)v0 * v0; q1 += (double)v1 * v1;
        q2 += (double)v2 * v2; q3 += (double)v3 * v3;
    }
    __shared__ double shS[4 * 64], shQ[4 * 64];
    if (grp == 0) {
#pragma unroll
        for (int k = 0; k < 4; ++k) {
            double sk = (k == 0) ? s0 : (k == 1) ? s1 : (k == 2) ? s2_ : s3;
            double qk = (k == 0) ? q0 : (k == 1) ? q1 : (k == 2) ? q2 : q3;
            shS[wv * 64 + sub * 4 + k] = sk;
            shQ[wv * 64 + sub * 4 + k] = qk;
        }
    }
    __syncthreads();
    if (wv == 0) {
        double a = shS[lane] + shS[64 + lane] + shS[128 + lane] + shS[192 + lane];
        double c = shQ[lane] + shQ[64 + lane] + shQ[128 + lane] + shQ[192 + lane];
        unsafeAtomicAdd(&sums[lane], a);
        unsafeAtomicAdd(&sums[64 + lane], c);
    }
}

// ---------------- head MLP + sigmoid (single block) -------------------------
__global__ void k_head(const double* __restrict__ sums,
                       const float* __restrict__ Wp1, const float* __restrict__ bp1,
                       const float* __restrict__ Wp2, const float* __restrict__ bp2,
                       const float* __restrict__ Wp3, const float* __restrict__ bp3,
                       float* __restrict__ out, int n) {
    __shared__ float comb[192], p1[64], p2[32];
    int t = threadIdx.x;
    if (t < 64) {
        double s = sums[t], s2 = sums[64 + t];
        double m = s / n;
        double var = (s2 - s * s / n) / (double)(n - 1);
        float mf = (float)m;
        float sd = (float)sqrt(var > 0.0 ? var : 0.0);
        comb[t] = mf;
        comb[64 + t] = mf;
        comb[128 + t] = sd;
    }
    __syncthreads();
    if (t < 64) {
        float acc = bp1[t];
        for (int k = 0; k < 192; ++k) acc = fmaf(comb[k], Wp1[k * 64 + t], acc);
        p1[t] = fmaxf(acc, 0.f);
    }
    __syncthreads();
    if (t < 32) {
        float acc = bp2[t];
        for (int k = 0; k < 64; ++k) acc = fmaf(p1[k], Wp2[k * 32 + t], acc);
        p2[t] = fmaxf(acc, 0.f);
    }
    __syncthreads();
    if (t == 0) {
        float acc = bp3[0];
        for (int k = 0; k < 32; ++k) acc = fmaf(p2[k], Wp3[k], acc);
        out[0] = 1.f / (1.f + expf(-acc));
    }
}

static inline char* align16(char* p) {
    return (char*)(((uintptr_t)p + 15) & ~(uintptr_t)15);
}

extern "C" void kernel_launch(void* const* d_in, const int* in_sizes, int n_in,
                              void* d_out, int out_size, void* d_ws, size_t ws_size,
                              hipStream_t stream) {
    const float* x   = (const float*)d_in[0];
    const int*   ei  = (const int*)d_in[1];
    const float* ea  = (const float*)d_in[2];
    const float* W1  = (const float*)d_in[3];
    const float* b1  = (const float*)d_in[4];
    const float* W2  = (const float*)d_in[5];
    const float* b2  = (const float*)d_in[6];
    const float* W3  = (const float*)d_in[7];
    const float* b3  = (const float*)d_in[8];
    const float* We1 = (const float*)d_in[9];
    const float* be1 = (const float*)d_in[10];
    const float* We2 = (const float*)d_in[11];
    const float* be2 = (const float*)d_in[12];
    const float* Wp1 = (const float*)d_in[13];
    const float* bp1 = (const float*)d_in[14];
    const float* Wp2 = (const float*)d_in[15];
    const float* bp2 = (const float*)d_in[16];
    const float* Wp3 = (const float*)d_in[17];
    const float* bp3 = (const float*)d_in[18];

    const int N = in_sizes[0] / 6;
    const int E = in_sizes[1] / 2;
    const int nbN = (N + 255) / 256;
    const int nbE = (E + 255) / 256;
    const int N8 = 8 * N;
    const size_t SB = ((size_t)N * 64 + 15) & ~(size_t)15;  // fp8 table 6.4MB

    // ---- workspace layout (~79 MB) ----
    char* p = (char*)d_ws;
    double* sums = (double*)p;          p = align16(p + 128 * sizeof(double));
    int* cntO8 = (int*)p;               p = align16(p + (size_t)N8 * 4);  // 3.2MB
    int* cntI8 = (int*)p;               p = align16(p + (size_t)N8 * 4);  // 3.2MB
    int* totO = (int*)p;                p = align16(p + (size_t)N * 4);
    int* totI = (int*)p;                p = align16(p + (size_t)N * 4);
    int* offO = (int*)p;                p = align16(p + ((size_t)N + 1) * 4);
    int* offI = (int*)p;                p = align16(p + ((size_t)N + 1) * 4);
    int2* bsum = (int2*)p;              p = align16(p + 512 * 8);
    float* dinv = (float*)p;            p = align16(p + (size_t)N * 4);
    int* in_src = (int*)p;              p = align16(p + (size_t)E * 4);
    uint4* in_rec = (uint4*)p;          p = align16(p + (size_t)E * 16);
    // U1: rankS/rankD (E*4 each) die after k_place -> sbufA/sbufB fp8 tables
    char* u1 = p;                       p = align16(p + 2 * SB);
    int* rankS = (int*)u1;
    int* rankD = (int*)(u1 + SB);
    unsigned* sbufA = (unsigned*)u1;
    unsigned* sbufB = (unsigned*)(u1 + SB);
    // U2: efp (E*8) + out_rec (E*8) die after k_nefmm1
    char* u2 = p;
    uint2* efp = (uint2*)u2;
    uint2* out_rec = (uint2*)(u2 + (size_t)E * 8);

    dim3 blk(256);

    k_zero<<<dim3((N8 + 255) / 256), blk, 0, stream>>>(cntO8, cntI8, sums, N8);
    k_front<<<dim3(nbE), blk, 0, stream>>>(ei, ea, We1, be1, We2, be2,
                                           efp, cntO8, cntI8, rankS, rankD, E, N);
    k_colscan<<<dim3(nbN), blk, 0, stream>>>(cntO8, cntI8, totO, totI, N);
    k_scan1<<<dim3(nbN), blk, 0, stream>>>(totO, totI, bsum, N);
    k_scan2<<<dim3(1), dim3(512), 0, stream>>>(bsum, nbN, offO + N, offI + N);
    k_scan3off<<<dim3(nbN), blk, 0, stream>>>(totO, totI, bsum, offO, offI, N);
    k_place<<<dim3(nbE), blk, 0, stream>>>(ei, rankS, rankD, offO, offI,
                                           cntO8, cntI8, efp, out_rec, in_rec, E, N);
    k_nefmm1<<<dim3(nbN), blk, 0, stream>>>(offO, out_rec, offI, in_rec, x, W1,
                                            dinv, in_src, sbufA, N);

    // layers 2,3 fused gather+mm; final fused gather+reduce
    k_gathermm<<<dim3(2048), blk, 0, stream>>>(offI, in_src, dinv, sbufA, b1, W2, sbufB, N);
    k_gathermm<<<dim3(2048), blk, 0, stream>>>(offI, in_src, dinv, sbufB, b2, W3, sbufA, N);
    k_gatherreduce<<<dim3(2048), blk, 0, stream>>>(offI, in_src, dinv, sbufA, b3, sums, N);
    k_head<<<dim3(1), dim3(64), 0, stream>>>(sums, Wp1, bp1, Wp2, bp2, Wp3, bp3,
                                             (float*)d_out, N);
}

// Round 15
// 599.496 us; speedup vs baseline: 1.0485x; 1.0485x over previous
//
#include <hip/hip_runtime.h>
#include <hip/hip_bf16.h>
#include <stdint.h>

typedef float floatx2 __attribute__((ext_vector_type(2)));
typedef unsigned uint32x4 __attribute__((ext_vector_type(4)));

__device__ __forceinline__ float rdlane(float v, int l) {
    return __uint_as_float(__builtin_amdgcn_readlane(__float_as_uint(v), l));
}
// pack floats -> fp8 e4m3 (HW cvt, RNE)
__device__ __forceinline__ unsigned pk_fp8x4(float a, float b, float c, float d) {
    int u = __builtin_amdgcn_cvt_pk_fp8_f32(a, b, 0, false);
    u = __builtin_amdgcn_cvt_pk_fp8_f32(c, d, u, true);
    return (unsigned)u;
}
__device__ __forceinline__ unsigned pk_fp8x2(float a, float b) {
    return (unsigned)__builtin_amdgcn_cvt_pk_fp8_f32(a, b, 0, false);
}

// ---------------- zero counters + pooled sums -------------------------------
__global__ void k_zero(int* __restrict__ cntO, int* __restrict__ cntI,
                       double* __restrict__ sums, int n) {
    int i = blockIdx.x * blockDim.x + threadIdx.x;
    if (i < 128) sums[i] = 0.0;
    if (i < n) { cntO[i] = 0; cntI[i] = 0; }
}

// ------- FUSED front: edge MLP (VALU) hides under 2 rank atomics/edge -------
// NOTE (R6/R14 negative results): device-scope atomics execute memory-side on
// gfx950 regardless of padding or XCD-partitioning — 2 atomics/edge is the
// structural floor of this kernel (~102MB RMW sector traffic, ~20G ops/s).
__global__ __launch_bounds__(256) void k_front(
    const int* __restrict__ ei, const float* __restrict__ ea,
    const float* __restrict__ We1, const float* __restrict__ be1,
    const float* __restrict__ We2, const float* __restrict__ be2,
    uint2* __restrict__ efp, int* __restrict__ cntO, int* __restrict__ cntI,
    int* __restrict__ rankS, int* __restrict__ rankD, int E) {
    __shared__ float sWe1[128], sbe1[64], sWe2[64 * 6], sbe2[6];
    int t = threadIdx.x;
    if (t < 128) sWe1[t] = We1[t];
    if (t < 64) {
        sbe1[t] = be1[t];
#pragma unroll
        for (int c = 0; c < 6; ++c) sWe2[t * 6 + c] = We2[t * 64 + c];
    }
    if (t < 6) sbe2[t] = be2[t];
    __syncthreads();

    int e = blockIdx.x * blockDim.x + t;
    if (e >= E) return;

    int s = ei[e], d = ei[E + e];
    int rs = atomicAdd(&cntO[s], 1);      // issue early; MLP overlaps RMW
    int rd = atomicAdd(&cntI[d], 1);

    float2 aa = ((const float2*)ea)[e];
    float acc[6];
#pragma unroll
    for (int c = 0; c < 6; ++c) acc[c] = sbe2[c];
#pragma unroll
    for (int j = 0; j < 64; ++j) {
        float h = fmaf(aa.x, sWe1[j], fmaf(aa.y, sWe1[64 + j], sbe1[j]));
        h = fmaxf(h, 0.f);
#pragma unroll
        for (int c = 0; c < 6; ++c) acc[c] = fmaf(h, sWe2[j * 6 + c], acc[c]);
    }
    efp[e] = make_uint2(pk_fp8x4(acc[0], acc[1], acc[2], acc[3]),
                        pk_fp8x2(acc[4], acc[5]));
    rankS[e] = rs;
    rankD[e] = rd;
}

// ---------------- fused int2 scan (3 passes) --------------------------------
__global__ __launch_bounds__(256) void k_scan1(const int* __restrict__ cntO,
                                               const int* __restrict__ cntI,
                                               int2* __restrict__ bsum, int n) {
    __shared__ int2 l[256];
    int i = blockIdx.x * 256 + threadIdx.x;
    l[threadIdx.x] = (i < n) ? make_int2(cntO[i], cntI[i]) : make_int2(0, 0);
    __syncthreads();
    for (int s = 128; s > 0; s >>= 1) {
        if (threadIdx.x < s) {
            l[threadIdx.x].x += l[threadIdx.x + s].x;
            l[threadIdx.x].y += l[threadIdx.x + s].y;
        }
        __syncthreads();
    }
    if (threadIdx.x == 0) bsum[blockIdx.x] = l[0];
}
__global__ __launch_bounds__(512) void k_scan2(int2* __restrict__ bsum, int nb,
                                               int* __restrict__ offON,
                                               int* __restrict__ offIN) {
    __shared__ int2 l[512];
    int t = threadIdx.x;
    int2 v = (t < nb) ? bsum[t] : make_int2(0, 0);
    l[t] = v;
    __syncthreads();
    for (int s = 1; s < 512; s <<= 1) {
        int2 tmp = (t >= s) ? l[t - s] : make_int2(0, 0);
        __syncthreads();
        l[t].x += tmp.x; l[t].y += tmp.y;
        __syncthreads();
    }
    if (t < nb) bsum[t] = make_int2(l[t].x - v.x, l[t].y - v.y);
    if (t == 511) { *offON = l[511].x; *offIN = l[511].y; }
}
__global__ __launch_bounds__(256) void k_scan3off(const int* __restrict__ cntO,
                                                  const int* __restrict__ cntI,
                                                  const int2* __restrict__ bsum,
                                                  int* __restrict__ offO,
                                                  int* __restrict__ offI, int n) {
    __shared__ int2 l[256];
    int i = blockIdx.x * 256 + threadIdx.x;
    int2 v = (i < n) ? make_int2(cntO[i], cntI[i]) : make_int2(0, 0);
    l[threadIdx.x] = v;
    __syncthreads();
    for (int s = 1; s < 256; s <<= 1) {
        int2 tmp = (threadIdx.x >= (unsigned)s) ? l[threadIdx.x - s] : make_int2(0, 0);
        __syncthreads();
        l[threadIdx.x].x += tmp.x; l[threadIdx.x].y += tmp.y;
        __syncthreads();
    }
    if (i < n) {
        int2 bs = bsum[blockIdx.x];
        offO[i] = l[threadIdx.x].x - v.x + bs.x;
        offI[i] = l[threadIdx.x].y - v.y + bs.y;
    }
}

// ------- CSR placement: 2 scattered stores/edge, fp8 ef embedded ------------
__global__ __launch_bounds__(256) void k_place(const int* __restrict__ ei,
                                               const int* __restrict__ rankS,
                                               const int* __restrict__ rankD,
                                               const int* __restrict__ offO,
                                               const int* __restrict__ offI,
                                               const uint2* __restrict__ efp,
                                               uint2* __restrict__ out_rec,
                                               uint4* __restrict__ in_rec, int E) {
    int e = blockIdx.x * blockDim.x + threadIdx.x;
    if (e >= E) return;
    int s = ei[e], d = ei[E + e];
    uint2 f = efp[e];
    out_rec[offO[s] + rankS[e]] = f;
    in_rec[offI[d] + rankD[e]] = make_uint4((unsigned)s, f.x, f.y, 0u);
}

// ------- per node: nef sums + dinv + in_src emit + FUSED layer-1 matmul -----
// output: single fp8 table, 64B rows (16 uints; uint c holds cols 4c..4c+3)
__global__ __launch_bounds__(256) void k_nefmm1(
    const int* __restrict__ offO, const uint2* __restrict__ out_rec,
    const int* __restrict__ offI, const uint4* __restrict__ in_rec,
    const float* __restrict__ x, const float* __restrict__ W1,
    float* __restrict__ dinv, int* __restrict__ in_src,
    unsigned* __restrict__ sOut, int n) {
    __shared__ float sW1[384];
    int t = threadIdx.x;
    for (int idx = t; idx < 384; idx += 256) sW1[idx] = W1[idx];
    __syncthreads();

    int i = blockIdx.x * blockDim.x + t;
    if (i >= n) return;
    int bo = offO[i], eo = offO[i + 1];
    int bi = offI[i], eiN = offI[i + 1];
    float a0 = 0.f, a1 = 0.f, a2 = 0.f, a3 = 0.f, a4 = 0.f, a5 = 0.f;
    for (int j = bo; j < eo; ++j) {
        uint2 q = out_rec[j];
        floatx2 p01 = __builtin_amdgcn_cvt_pk_f32_fp8(q.x, false);
        floatx2 p23 = __builtin_amdgcn_cvt_pk_f32_fp8(q.x, true);
        floatx2 p45 = __builtin_amdgcn_cvt_pk_f32_fp8(q.y, false);
        a0 += p01.x; a1 += p01.y; a2 += p23.x;
        a3 += p23.y; a4 += p45.x; a5 += p45.y;
    }
    for (int j = bi; j < eiN; ++j) {
        uint4 r = in_rec[j];
        __builtin_nontemporal_store((int)r.x, in_src + j);   // compact stream
        floatx2 p01 = __builtin_amdgcn_cvt_pk_f32_fp8(r.y, false);
        floatx2 p23 = __builtin_amdgcn_cvt_pk_f32_fp8(r.y, true);
        floatx2 p45 = __builtin_amdgcn_cvt_pk_f32_fp8(r.z, false);
        a0 += p01.x; a1 += p01.y; a2 += p23.x;
        a3 += p23.y; a4 += p45.x; a5 += p45.y;
    }
    int indeg = eiN - bi;
    float degf = (float)((eo - bo) + indeg);
    float inv = 0.5f / fmaxf(degf, 1.f);
    const float2* xr = (const float2*)(x + (size_t)i * 6);
    float2 x01 = xr[0], x23 = xr[1], x45 = xr[2];
    float xp0 = x01.x + a0 * inv, xp1 = x01.y + a1 * inv;
    float xp2 = x23.x + a2 * inv, xp3 = x23.y + a3 * inv;
    float xp4 = x45.x + a4 * inv, xp5 = x45.y + a5 * inv;
    float dv = 1.f / sqrtf(1.f + (float)indeg);
    dinv[i] = dv;

    // layer 1: s1 = fp8(dv * (xp @ W1)) -> 16 packed uints
    unsigned u[16];
#pragma unroll
    for (int c4 = 0; c4 < 16; ++c4) {
        float tv[4];
#pragma unroll
        for (int k = 0; k < 4; ++k) {
            int c = c4 * 4 + k;
            float v = xp0 * sW1[c] + xp1 * sW1[64 + c] + xp2 * sW1[128 + c]
                    + xp3 * sW1[192 + c] + xp4 * sW1[256 + c] + xp5 * sW1[320 + c];
            tv[k] = v * dv;
        }
        u[c4] = pk_fp8x4(tv[0], tv[1], tv[2], tv[3]);
    }
#pragma unroll
    for (int q4 = 0; q4 < 4; ++q4) {
        uint32x4 v = {u[q4 * 4 + 0], u[q4 * 4 + 1], u[q4 * 4 + 2], u[q4 * 4 + 3]};
        __builtin_nontemporal_store(v, (uint32x4*)(sOut + (size_t)i * 16) + q4);
    }
}

// ------- FUSED gather+mm, fp8 rows (64B): 16 lanes x uint per row -----------
__global__ __launch_bounds__(256) void k_gathermm(
    const int* __restrict__ offI, const int* __restrict__ in_src,
    const float* __restrict__ dinv, const unsigned* __restrict__ sIn,
    const float* __restrict__ bias, const float* __restrict__ W,
    unsigned* __restrict__ sOut, int n) {
    int lane = threadIdx.x & 63;
    int sub = lane & 15, grp = lane >> 4;
    int wid = (blockIdx.x * blockDim.x + threadIdx.x) >> 6;
    int nw = (gridDim.x * blockDim.x) >> 6;
    float w[64];
#pragma unroll
    for (int c = 0; c < 64; ++c) w[c] = W[c * 64 + lane];
    float4 bb = ((const float4*)bias)[sub];

    for (int i = wid; i < n; i += nw) {
        unsigned su = sIn[(size_t)i * 16 + sub];
        float a0, a1, a2, a3;
        if (grp == 0) {
            floatx2 lo = __builtin_amdgcn_cvt_pk_f32_fp8(su, false);
            floatx2 hi = __builtin_amdgcn_cvt_pk_f32_fp8(su, true);
            a0 = lo.x; a1 = lo.y; a2 = hi.x; a3 = hi.y;
        } else { a0 = a1 = a2 = a3 = 0.f; }
        int b0 = offI[i], e0 = offI[i + 1];
#pragma unroll 4
        for (int j = b0 + grp; j < e0; j += 4) {
            unsigned src = (unsigned)__builtin_nontemporal_load(in_src + j);
            unsigned u = sIn[(size_t)src * 16 + sub];
            floatx2 lo = __builtin_amdgcn_cvt_pk_f32_fp8(u, false);
            floatx2 hi = __builtin_amdgcn_cvt_pk_f32_fp8(u, true);
            a0 += lo.x; a1 += lo.y; a2 += hi.x; a3 += hi.y;
        }
        a0 += __shfl_xor(a0, 16); a1 += __shfl_xor(a1, 16);
        a2 += __shfl_xor(a2, 16); a3 += __shfl_xor(a3, 16);
        a0 += __shfl_xor(a0, 32); a1 += __shfl_xor(a1, 32);
        a2 += __shfl_xor(a2, 32); a3 += __shfl_xor(a3, 32);

        float dv = dinv[i];
        float h0 = fmaxf(fmaf(a0, dv, bb.x), 0.f);
        float h1 = fmaxf(fmaf(a1, dv, bb.y), 0.f);
        float h2 = fmaxf(fmaf(a2, dv, bb.z), 0.f);
        float h3 = fmaxf(fmaf(a3, dv, bb.w), 0.f);
        float o = 0.f;
#pragma unroll
        for (int g = 0; g < 16; ++g) {
            o = fmaf(rdlane(h0, g), w[g * 4 + 0], o);
            o = fmaf(rdlane(h1, g), w[g * 4 + 1], o);
            o = fmaf(rdlane(h2, g), w[g * 4 + 2], o);
            o = fmaf(rdlane(h3, g), w[g * 4 + 3], o);
        }
        o *= dv;
        float o0 = __shfl(o, sub * 4 + 0);
        float o1 = __shfl(o, sub * 4 + 1);
        float o2 = __shfl(o, sub * 4 + 2);
        float o3 = __shfl(o, sub * 4 + 3);
        if (lane < 16)
            __builtin_nontemporal_store(pk_fp8x4(o0, o1, o2, o3),
                                        sOut + (size_t)i * 16 + lane);
    }
}

// ------- FUSED final gather + b3 + pooled sum/sumsq, fp8 rows ---------------
__global__ __launch_bounds__(256) void k_gatherreduce(
    const int* __restrict__ offI, const int* __restrict__ in_src,
    const float* __restrict__ dinv, const unsigned* __restrict__ sIn,
    const float* __restrict__ b3, double* __restrict__ sums, int n) {
    int lane = threadIdx.x & 63;
    int sub = lane & 15, grp = lane >> 4;
    int wv = threadIdx.x >> 6;
    int wid = (blockIdx.x * blockDim.x + threadIdx.x) >> 6;
    int nw = (gridDim.x * blockDim.x) >> 6;
    float4 bb = ((const float4*)b3)[sub];
    double s0 = 0.0, s1 = 0.0, s2_ = 0.0, s3 = 0.0;
    double q0 = 0.0, q1 = 0.0, q2 = 0.0, q3 = 0.0;

    for (int i = wid; i < n; i += nw) {
        unsigned su = sIn[(size_t)i * 16 + sub];
        float a0, a1, a2, a3;
        if (grp == 0) {
            floatx2 lo = __builtin_amdgcn_cvt_pk_f32_fp8(su, false);
            floatx2 hi = __builtin_amdgcn_cvt_pk_f32_fp8(su, true);
            a0 = lo.x; a1 = lo.y; a2 = hi.x; a3 = hi.y;
        } else { a0 = a1 = a2 = a3 = 0.f; }
        int b0 = offI[i], e0 = offI[i + 1];
#pragma unroll 4
        for (int j = b0 + grp; j < e0; j += 4) {
            unsigned src = (unsigned)__builtin_nontemporal_load(in_src + j);
            unsigned u = sIn[(size_t)src * 16 + sub];
            floatx2 lo = __builtin_amdgcn_cvt_pk_f32_fp8(u, false);
            floatx2 hi = __builtin_amdgcn_cvt_pk_f32_fp8(u, true);
            a0 += lo.x; a1 += lo.y; a2 += hi.x; a3 += hi.y;
        }
        a0 += __shfl_xor(a0, 16); a1 += __shfl_xor(a1, 16);
        a2 += __shfl_xor(a2, 16); a3 += __shfl_xor(a3, 16);
        a0 += __shfl_xor(a0, 32); a1 += __shfl_xor(a1, 32);
        a2 += __shfl_xor(a2, 32); a3 += __shfl_xor(a3, 32);

        float dv = dinv[i];
        float v0 = fmaf(a0, dv, bb.x);
        float v1 = fmaf(a1, dv, bb.y);
        float v2 = fmaf(a2, dv, bb.z);
        float v3 = fmaf(a3, dv, bb.w);
        s0 += v0; s1 += v1; s2_ += v2; s3 += v3;
        q0 += (double)v0 * v0; q1 += (double)v1 * v1;
        q2 += (double)v2 * v2; q3 += (double)v3 * v3;
    }
    __shared__ double shS[4 * 64], shQ[4 * 64];
    if (grp == 0) {
#pragma unroll
        for (int k = 0; k < 4; ++k) {
            double sk = (k == 0) ? s0 : (k == 1) ? s1 : (k == 2) ? s2_ : s3;
            double qk = (k == 0) ? q0 : (k == 1) ? q1 : (k == 2) ? q2 : q3;
            shS[wv * 64 + sub * 4 + k] = sk;
            shQ[wv * 64 + sub * 4 + k] = qk;
        }
    }
    __syncthreads();
    if (wv == 0) {
        double a = shS[lane] + shS[64 + lane] + shS[128 + lane] + shS[192 + lane];
        double c = shQ[lane] + shQ[64 + lane] + shQ[128 + lane] + shQ[192 + lane];
        unsafeAtomicAdd(&sums[lane], a);
        unsafeAtomicAdd(&sums[64 + lane], c);
    }
}

// ---------------- head MLP + sigmoid (single block) -------------------------
__global__ void k_head(const double* __restrict__ sums,
                       const float* __restrict__ Wp1, const float* __restrict__ bp1,
                       const float* __restrict__ Wp2, const float* __restrict__ bp2,
                       const float* __restrict__ Wp3, const float* __restrict__ bp3,
                       float* __restrict__ out, int n) {
    __shared__ float comb[192], p1[64], p2[32];
    int t = threadIdx.x;
    if (t < 64) {
        double s = sums[t], s2 = sums[64 + t];
        double m = s / n;
        double var = (s2 - s * s / n) / (double)(n - 1);
        float mf = (float)m;
        float sd = (float)sqrt(var > 0.0 ? var : 0.0);
        comb[t] = mf;
        comb[64 + t] = mf;
        comb[128 + t] = sd;
    }
    __syncthreads();
    if (t < 64) {
        float acc = bp1[t];
        for (int k = 0; k < 192; ++k) acc = fmaf(comb[k], Wp1[k * 64 + t], acc);
        p1[t] = fmaxf(acc, 0.f);
    }
    __syncthreads();
    if (t < 32) {
        float acc = bp2[t];
        for (int k = 0; k < 64; ++k) acc = fmaf(p1[k], Wp2[k * 32 + t], acc);
        p2[t] = fmaxf(acc, 0.f);
    }
    __syncthreads();
    if (t == 0) {
        float acc = bp3[0];
        for (int k = 0; k < 32; ++k) acc = fmaf(p2[k], Wp3[k], acc);
        out[0] = 1.f / (1.f + expf(-acc));
    }
}

static inline char* align16(char* p) {
    return (char*)(((uintptr_t)p + 15) & ~(uintptr_t)15);
}

extern "C" void kernel_launch(void* const* d_in, const int* in_sizes, int n_in,
                              void* d_out, int out_size, void* d_ws, size_t ws_size,
                              hipStream_t stream) {
    const float* x   = (const float*)d_in[0];
    const int*   ei  = (const int*)d_in[1];
    const float* ea  = (const float*)d_in[2];
    const float* W1  = (const float*)d_in[3];
    const float* b1  = (const float*)d_in[4];
    const float* W2  = (const float*)d_in[5];
    const float* b2  = (const float*)d_in[6];
    const float* W3  = (const float*)d_in[7];
    const float* b3  = (const float*)d_in[8];
    const float* We1 = (const float*)d_in[9];
    const float* be1 = (const float*)d_in[10];
    const float* We2 = (const float*)d_in[11];
    const float* be2 = (const float*)d_in[12];
    const float* Wp1 = (const float*)d_in[13];
    const float* bp1 = (const float*)d_in[14];
    const float* Wp2 = (const float*)d_in[15];
    const float* bp2 = (const float*)d_in[16];
    const float* Wp3 = (const float*)d_in[17];
    const float* bp3 = (const float*)d_in[18];

    const int N = in_sizes[0] / 6;
    const int E = in_sizes[1] / 2;
    const int nbN = (N + 255) / 256;
    const int nbE = (E + 255) / 256;
    const size_t SB = ((size_t)N * 64 + 15) & ~(size_t)15;  // fp8 table 6.4MB (== E*4)

    // ---- workspace layout (~72 MB) ----
    char* p = (char*)d_ws;
    double* sums = (double*)p;          p = align16(p + 128 * sizeof(double));
    int* cntO = (int*)p;                p = align16(p + (size_t)N * 4);
    int* cntI = (int*)p;                p = align16(p + (size_t)N * 4);
    int* offO = (int*)p;                p = align16(p + ((size_t)N + 1) * 4);
    int* offI = (int*)p;                p = align16(p + ((size_t)N + 1) * 4);
    int2* bsum = (int2*)p;              p = align16(p + 512 * 8);
    float* dinv = (float*)p;            p = align16(p + (size_t)N * 4);
    int* in_src = (int*)p;              p = align16(p + (size_t)E * 4);
    uint4* in_rec = (uint4*)p;          p = align16(p + (size_t)E * 16);
    // U1: rankS/rankD (E*4 each) die after k_place -> sbufA/sbufB fp8 tables
    char* u1 = p;                       p = align16(p + 2 * SB);
    int* rankS = (int*)u1;
    int* rankD = (int*)(u1 + SB);
    unsigned* sbufA = (unsigned*)u1;
    unsigned* sbufB = (unsigned*)(u1 + SB);
    // U2: efp (E*8) + out_rec (E*8) die after k_nefmm1
    char* u2 = p;
    uint2* efp = (uint2*)u2;
    uint2* out_rec = (uint2*)(u2 + (size_t)E * 8);

    dim3 blk(256);

    k_zero<<<dim3(nbN), blk, 0, stream>>>(cntO, cntI, sums, N);
    k_front<<<dim3(nbE), blk, 0, stream>>>(ei, ea, We1, be1, We2, be2,
                                           efp, cntO, cntI, rankS, rankD, E);
    k_scan1<<<dim3(nbN), blk, 0, stream>>>(cntO, cntI, bsum, N);
    k_scan2<<<dim3(1), dim3(512), 0, stream>>>(bsum, nbN, offO + N, offI + N);
    k_scan3off<<<dim3(nbN), blk, 0, stream>>>(cntO, cntI, bsum, offO, offI, N);
    k_place<<<dim3(nbE), blk, 0, stream>>>(ei, rankS, rankD, offO, offI, efp,
                                           out_rec, in_rec, E);
    k_nefmm1<<<dim3(nbN), blk, 0, stream>>>(offO, out_rec, offI, in_rec, x, W1,
                                            dinv, in_src, sbufA, N);

    // layers 2,3 fused gather+mm; final fused gather+reduce
    k_gathermm<<<dim3(2048), blk, 0, stream>>>(offI, in_src, dinv, sbufA, b1, W2, sbufB, N);
    k_gathermm<<<dim3(2048), blk, 0, stream>>>(offI, in_src, dinv, sbufB, b2, W3, sbufA, N);
    k_gatherreduce<<<dim3(2048), blk, 0, stream>>>(offI, in_src, dinv, sbufA, b3, sums, N);
    k_head<<<dim3(1), dim3(64), 0, stream>>>(sums, Wp1, bp1, Wp2, bp2, Wp3, bp3,
                                             (float*)d_out, N);
}